// Round 11
// baseline (1375.230 us; speedup 1.0000x reference)
//
#include <hip/hip_runtime.h>
#include <hip/hip_fp16.h>
#include <math.h>

#define CAP 4096
#define P_TOT 20267
#define PAD_N 21267

typedef unsigned short ushort_t;
typedef __attribute__((ext_vector_type(8))) _Float16 f16x8;
typedef __attribute__((ext_vector_type(8))) short s16x8;
typedef __attribute__((ext_vector_type(4))) float f32x4;

struct LvlSrc { const float* p[5]; };
struct Cand { float score; int level; int ai; int lb; float b0,b1,b2,b3; };
struct ConvArgs {
    const ushort_t* Ah[2]; const ushort_t* Al[2];   // conv MFMA inputs (fp16 hi + lo)
    ushort_t* Oh[2]; ushort_t* Ol[2];               // epilogue stores hi+lo
    const float* bias[2];
    int brow0[2];
};
struct PadPtrs { ushort_t* p[8]; };

__constant__ int d_H[5]    = {100,50,25,13,7};
__constant__ int d_W[5]    = {152,76,38,19,10};
__constant__ int d_WP[5]   = {154,78,40,21,12};
__constant__ int d_HP[5]   = {102,52,27,15,9};
__constant__ int d_HW[5]   = {15200,3800,950,247,70};
__constant__ int d_LOFF[6] = {0,15200,19000,19950,20197,20267};
__constant__ int d_POFF[6] = {0,15708,19764,20844,21159,21267};
__constant__ int d_PT[6]   = {0,119,149,157,159,160};      // 128-px tiles cumsum (final conv)
__constant__ int d_PT2[6]  = {0,238,298,313,317,319};      // 64-px tiles cumsum (towers)
__constant__ int d_RC[6]   = {0,508,764,894,962,1000};     // border-ring pixel cumsum

__device__ __forceinline__ ushort_t f2h(float x) { return __half_as_ushort(__float2half(x)); }
__device__ __forceinline__ float h2f(ushort_t u) { return __half2float(__ushort_as_half(u)); }

// ---------- zero the 1-px halo ring of all 8 padded buffers --------------------------
__global__ void zero_pad_k(PadPtrs bufs)
{
    int idx = blockIdx.x*256 + threadIdx.x;          // 1000 ring px * 2 n * 32 cs
    if (idx >= 64000) return;
    int cs = idx & 31;
    int rest = idx >> 5;
    int n = rest & 1;
    int r = rest >> 1;
    int l = 0; while (l < 4 && r >= d_RC[l+1]) ++l;
    r -= d_RC[l];
    int WP = d_WP[l], HP = d_HP[l];
    int y, x;
    if (r < WP)            { y = 0;      x = r; }
    else if (r < 2*WP)     { y = HP-1;   x = r - WP; }
    else { int s = r - 2*WP; y = 1 + (s >> 1); x = (s & 1) ? WP-1 : 0; }
    size_t a = ((size_t)(n*PAD_N + d_POFF[l] + y*WP + x))*256 + cs*8;
    s16x8 z = (s16x8){0,0,0,0,0,0,0,0};
#pragma unroll
    for (int i = 0; i < 8; ++i) *(s16x8*)(bufs.p[i] + a) = z;
}

// ---------- ws-too-small sentinel ----------------------------------------------------
__global__ void sentinel_k(float* out, int nsz)
{
    int i = blockIdx.x*256 + threadIdx.x;
    if (i < nsz) out[i] = 12345.0f;
}

// ---------- one-shot weight prep (fp16 hi) -------------------------------------------
// rows [0,1024)=cls tower, [1024,2048)=reg tower, [2048,2944)=final cls
__global__ void prepw_k(const float* __restrict__ cls_tw, const float* __restrict__ reg_tw,
                        const float* __restrict__ cls_w, ushort_t* __restrict__ bh)
{
    size_t total = (size_t)2944*2304;
    for (size_t idx = (size_t)blockIdx.x*256 + threadIdx.x; idx < total; idx += (size_t)gridDim.x*256) {
        int k = (int)(idx % 2304); int row = (int)(idx / 2304);
        int tap = k >> 8; int ci = k & 255;
        float v;
        if (row < 1024)        v = cls_tw[(size_t)row*2304 + ci*9 + tap];
        else if (row < 2048)   v = reg_tw[(size_t)(row-1024)*2304 + ci*9 + tap];
        else { int co = row - 2048; v = (co < 819) ? cls_w[(size_t)co*2304 + ci*9 + tap] : 0.f; }
        bh[idx] = f2h(v);
    }
}

// ---------- input NCHW fp32 -> padded NHWC fp16 hi/lo --------------------------------
__global__ __launch_bounds__(256)
void conv_in_k(LvlSrc src, ushort_t* __restrict__ ph, ushort_t* __restrict__ pl)
{
    int total = 2*32*P_TOT;
    for (int idx = blockIdx.x*256 + threadIdx.x; idx < total; idx += gridDim.x*256) {
        int pix = idx % P_TOT;
        int cs  = (idx / P_TOT) & 31;
        int n   = idx / (32*P_TOT);
        int l = 0; while (l < 4 && pix >= d_LOFF[l+1]) ++l;
        int p = pix - d_LOFF[l];
        int W = d_W[l], WP = d_WP[l], HW = d_HW[l];
        int y = p / W, x = p % W;
        const float* sp = src.p[l];
        size_t a = ((size_t)(n*PAD_N + d_POFF[l] + (y+1)*WP + (x+1)))*256 + cs*8;
        s16x8 vh, vl;
#pragma unroll
        for (int j = 0; j < 8; ++j) {
            float v = sp[((size_t)(n*256 + cs*8 + j))*HW + p];
            ushort_t h = f2h(v);
            vh[j] = (short)h;
            vl[j] = (short)f2h(v - h2f(h));
        }
        *(s16x8*)(ph + a) = vh;
        *(s16x8*)(pl + a) = vl;
    }
}

// ---------- TOWER conv3x3: fp16-split 2-pass, 64px x 256co block, 32KB LDS -----------
// Tile 64px x 128co per (cot), 4 waves (2px x 2co), wave tile 32px x 64co.
// Same K order as before -> bitwise-identical conv outputs.
__global__ __launch_bounds__(256, 4)
void conv_tower_k(ConvArgs args, const ushort_t* __restrict__ Bh,
                  float* __restrict__ partials)
{
    __shared__ __align__(16) ushort_t smem[16384];   // 32KB
    ushort_t* sAh = smem;            // [64][64]
    ushort_t* sAl = smem + 4096;     // [64][64]
    ushort_t* sBh = smem + 8192;     // [128][64]

    int b = blockIdx.x;
    int widx = (b & 7)*319 + (b >> 3);                // bijective (2552 = 8*319)
    int pt = widx >> 3, t2 = widx & 7;                // pt-major: siblings share A window
    int n = t2 & 1, cot = (t2 >> 1) & 1, tw = t2 >> 2;
    int brow = args.brow0[tw] + cot*128;

    int l = 0; while (l < 4 && pt >= d_PT2[l+1]) ++l;
    int p0 = (pt - d_PT2[l])*64;
    int Pl = d_HW[l], W = d_W[l], WP = d_WP[l];
    const ushort_t* Ah = args.Ah[tw];
    const ushort_t* Al = args.Al[tw];

    int tid = threadIdx.x;
    int w = tid >> 6, ln = tid & 63;
    int wr = w >> 1, wc = w & 1;

    int srow = w*8 + (ln >> 3);                       // 0..31
    int swz  = ((ln & 7) ^ (ln >> 3)) << 3;           // inverse-swizzled source granule
    size_t abase[2];
#pragma unroll
    for (int it = 0; it < 2; ++it) {
        int row = it*32 + srow;                       // 0..63
        int p = min(p0 + row, Pl - 1);
        int y = p / W, x = p - y*W;
        abase[it] = ((size_t)(n*PAD_N + d_POFF[l] + y*WP + x))*256 + swz;
    }
    size_t bbase[4];
#pragma unroll
    for (int it = 0; it < 4; ++it)
        bbase[it] = ((size_t)(brow + it*32 + srow))*2304 + swz;
    int ldso = w*1024;                                // + it*4096 bytes

    int kbase = (ln >> 4) * 8;
    int rowA[2], xrA[2], rowB[4], xrB[4];
#pragma unroll
    for (int m = 0; m < 2; ++m) {
        int r = wr*32 + m*16 + (ln & 15);
        rowA[m] = r*64; xrA[m] = (r & 7) << 3;
    }
#pragma unroll
    for (int nf = 0; nf < 4; ++nf) {
        int r = wc*64 + nf*16 + (ln & 15);
        rowB[nf] = r*64; xrB[nf] = (r & 7) << 3;
    }

    f32x4 acc[2][4];
#pragma unroll
    for (int m = 0; m < 2; ++m)
#pragma unroll
        for (int nf = 0; nf < 4; ++nf) acc[m][nf] = (f32x4){0.f,0.f,0.f,0.f};

    // ks -> (ky, sl, kx): ks = ky*12 + sl*3 + kx (same order as prior rounds)
    auto stage = [&](int ks) {
        int ky = ks / 12;
        int rem = ks - ky*12;
        int sl = rem / 3;
        int kx = rem - sl*3;
        size_t adelta = (size_t)(ky*WP + kx)*256 + sl*64;
        size_t bdelta = (size_t)((ky*3 + kx)*256 + sl*64);
#pragma unroll
        for (int it = 0; it < 2; ++it) {
            __builtin_amdgcn_global_load_lds((const unsigned int*)(Ah + abase[it] + adelta),
                                             (unsigned int*)((char*)sAh + it*4096 + ldso), 16, 0, 0);
            __builtin_amdgcn_global_load_lds((const unsigned int*)(Al + abase[it] + adelta),
                                             (unsigned int*)((char*)sAl + it*4096 + ldso), 16, 0, 0);
        }
#pragma unroll
        for (int it = 0; it < 4; ++it)
            __builtin_amdgcn_global_load_lds((const unsigned int*)(Bh + bbase[it] + bdelta),
                                             (unsigned int*)((char*)sBh + it*4096 + ldso), 16, 0, 0);
    };

    stage(0);
    for (int ks = 0; ks < 36; ++ks) {
        __syncthreads();                 // stage(ks) landed (barrier drains vmcnt)
        f16x8 a_h[2][2], a_l[2][2], b_h[2][4];
#pragma unroll
        for (int ks2 = 0; ks2 < 2; ++ks2) {
            int kb = kbase + ks2*32;
#pragma unroll
            for (int m = 0; m < 2; ++m) {
                int idx = rowA[m] + (kb ^ xrA[m]);
                a_h[ks2][m] = *(const f16x8*)&sAh[idx];
                a_l[ks2][m] = *(const f16x8*)&sAl[idx];
            }
#pragma unroll
            for (int nf = 0; nf < 4; ++nf) {
                int idx = rowB[nf] + (kb ^ xrB[nf]);
                b_h[ks2][nf] = *(const f16x8*)&sBh[idx];
            }
        }
        __syncthreads();                 // frag reads complete -> LDS reusable
        if (ks + 1 < 36) stage(ks + 1);  // next stage flies under the MFMAs below
        __builtin_amdgcn_sched_barrier(0);
#pragma unroll
        for (int ks2 = 0; ks2 < 2; ++ks2)
#pragma unroll
            for (int m = 0; m < 2; ++m)
#pragma unroll
                for (int nf = 0; nf < 4; ++nf) {
                    acc[m][nf] = __builtin_amdgcn_mfma_f32_16x16x32_f16(a_h[ks2][m], b_h[ks2][nf], acc[m][nf], 0, 0, 0);
                    acc[m][nf] = __builtin_amdgcn_mfma_f32_16x16x32_f16(a_l[ks2][m], b_h[ks2][nf], acc[m][nf], 0, 0, 0);
                }
    }

    // epilogue: bias + hi/lo store + deterministic GN partials
    ushort_t* Oh = args.Oh[tw];
    ushort_t* Ol = args.Ol[tw];
    const float* bias = args.bias[tw];
    float S[4] = {0,0,0,0}, Q[4] = {0,0,0,0};
#pragma unroll
    for (int m = 0; m < 2; ++m) {
        size_t pa[4]; bool ok[4];
#pragma unroll
        for (int r = 0; r < 4; ++r) {
            int p_row = p0 + wr*32 + m*16 + (ln >> 4)*4 + r;
            ok[r] = p_row < Pl;
            int pr = ok[r] ? p_row : 0;
            int y = pr / W, x = pr - y*W;
            pa[r] = ((size_t)(n*PAD_N + d_POFF[l] + (y+1)*WP + (x+1)))*256;
        }
#pragma unroll
        for (int nf = 0; nf < 4; ++nf) {
            int co = cot*128 + wc*64 + nf*16 + (ln & 15);
            float bs = bias[co];
#pragma unroll
            for (int r = 0; r < 4; ++r) if (ok[r]) {
                float v = acc[m][nf][r] + bs;
                ushort_t h = f2h(v);
                Oh[pa[r] + co] = h;
                Ol[pa[r] + co] = f2h(v - h2f(h));
                S[nf] += v; Q[nf] += v*v;
            }
        }
    }
    __syncthreads();
    float* redS = (float*)smem;        // 1024
    float* redQ = redS + 1024;         // 1024
    float* colS = redQ + 1024;         // 128
    float* colQ = colS + 128;          // 128
#pragma unroll
    for (int nf = 0; nf < 4; ++nf) {
        int co_l = wc*64 + nf*16 + (ln & 15);
        redS[co_l*8 + wr*4 + (ln >> 4)] = S[nf];
        redQ[co_l*8 + wr*4 + (ln >> 4)] = Q[nf];
    }
    __syncthreads();
    if (tid < 128) {
        float s = 0.f, qq = 0.f;
#pragma unroll
        for (int j = 0; j < 8; ++j) { s += redS[tid*8 + j]; qq += redQ[tid*8 + j]; }
        colS[tid] = s; colQ[tid] = qq;
    }
    __syncthreads();
    if (tid < 16) {
        float s = 0.f, qq = 0.f;
#pragma unroll
        for (int j = 0; j < 8; ++j) { s += colS[tid*8 + j]; qq += colQ[tid*8 + j]; }
        partials[((size_t)widx*16 + tid)*2]     = s;
        partials[((size_t)widx*16 + tid)*2 + 1] = qq;
    }
}

// ---------- FINAL cls conv: fp16 single-pass + prefilter (unchanged from R10) --------
__global__ __launch_bounds__(256)
void conv_detect_k(const ushort_t* __restrict__ Ah, const ushort_t* __restrict__ Bh,
                   const float* __restrict__ fbias, unsigned* __restrict__ pcand,
                   int* __restrict__ pccnt)
{
    __shared__ __align__(16) ushort_t smem[2*8192];
    ushort_t* sAh = smem;
    ushort_t* sBh = smem + 8192;

    int b = blockIdx.x;
    int widx = (b & 7)*280 + (b >> 3);
    int pt = widx / 14, t2 = widx - pt*14;            // 14 siblings share A window
    int n = t2 & 1, cot = t2 >> 1;
    int brow = 2048 + cot*128;

    int l = 0; while (l < 4 && pt >= d_PT[l+1]) ++l;
    int p0 = (pt - d_PT[l])*128;
    int Pl = d_HW[l], W = d_W[l], WP = d_WP[l];

    int tid = threadIdx.x;
    int w = tid >> 6, ln = tid & 63;
    int wr = w >> 1, wc = w & 1;

    size_t abase[4]; size_t bbase[4]; int ldso[4];
#pragma unroll
    for (int it = 0; it < 4; ++it) {
        int ch = (it*4 + w)*8 + (ln >> 3);
        int swz = ((ln & 7) ^ (ch & 7)) << 3;
        int p = min(p0 + ch, Pl - 1);
        int y = p / W, x = p % W;
        abase[it] = ((size_t)(n*PAD_N + d_POFF[l] + y*WP + x))*256 + swz;
        bbase[it] = ((size_t)(brow + ch))*2304 + swz;
        ldso[it]  = (it*4 + w)*1024;
    }

    int kbase = (ln >> 4) * 8;
    int rowA[4], xrA[4], rowB[4], xrB[4];
#pragma unroll
    for (int m = 0; m < 4; ++m) {
        int r = wr*64 + m*16 + (ln & 15);
        rowA[m] = r*64; xrA[m] = (r & 7) << 3;
    }
#pragma unroll
    for (int nf = 0; nf < 4; ++nf) {
        int r = wc*64 + nf*16 + (ln & 15);
        rowB[nf] = r*64; xrB[nf] = (r & 7) << 3;
    }

    f32x4 acc[4][4];
#pragma unroll
    for (int m = 0; m < 4; ++m)
#pragma unroll
        for (int nf = 0; nf < 4; ++nf) acc[m][nf] = (f32x4){0.f,0.f,0.f,0.f};

    auto stage = [&](int ks) {
        int ky = ks / 12;
        int rem = ks - ky*12;
        int sl = rem / 3;
        int kx = rem - sl*3;
        size_t adelta = (size_t)(ky*WP + kx)*256 + sl*64;
        size_t bdelta = (size_t)((ky*3 + kx)*256 + sl*64);
#pragma unroll
        for (int it = 0; it < 4; ++it) {
            __builtin_amdgcn_global_load_lds((const unsigned int*)(Ah + abase[it] + adelta),
                                             (unsigned int*)((char*)sAh + ldso[it]), 16, 0, 0);
            __builtin_amdgcn_global_load_lds((const unsigned int*)(Bh + bbase[it] + bdelta),
                                             (unsigned int*)((char*)sBh + ldso[it]), 16, 0, 0);
        }
    };

    stage(0);
    for (int ks = 0; ks < 36; ++ks) {
        __syncthreads();
        f16x8 a_h[2][4], b_h[2][4];
#pragma unroll
        for (int ks2 = 0; ks2 < 2; ++ks2) {
            int kb = kbase + ks2*32;
#pragma unroll
            for (int m = 0; m < 4; ++m)
                a_h[ks2][m] = *(const f16x8*)&sAh[rowA[m] + (kb ^ xrA[m])];
#pragma unroll
            for (int nf = 0; nf < 4; ++nf)
                b_h[ks2][nf] = *(const f16x8*)&sBh[rowB[nf] + (kb ^ xrB[nf])];
        }
        __syncthreads();
        if (ks + 1 < 36) stage(ks + 1);
        __builtin_amdgcn_sched_barrier(0);
#pragma unroll
        for (int ks2 = 0; ks2 < 2; ++ks2)
#pragma unroll
            for (int m = 0; m < 4; ++m)
#pragma unroll
                for (int nf = 0; nf < 4; ++nf)
                    acc[m][nf] = __builtin_amdgcn_mfma_f32_16x16x32_f16(a_h[ks2][m], b_h[ks2][nf], acc[m][nf], 0, 0, 0);
    }

    // prefilter: single-pass logit approx; margin 0.25 vs threshold -2.944 (~60 sigma)
    int pixbase = p0 + wr*64;
#pragma unroll
    for (int m = 0; m < 4; ++m)
#pragma unroll
        for (int nf = 0; nf < 4; ++nf) {
            int co = cot*128 + wc*64 + nf*16 + (ln & 15);
            if (co < 819) {
                float bs = fbias[co];
#pragma unroll
                for (int r = 0; r < 4; ++r) {
                    int p_row = pixbase + m*16 + (ln >> 4)*4 + r;
                    if (p_row < Pl) {
                        float logit = acc[m][nf][r] + bs;
                        if (logit > -3.2f) {
                            int idx = atomicAdd(&pccnt[n], 1);
                            if (idx < CAP)
                                pcand[n*CAP + idx] = ((unsigned)l << 24) | ((unsigned)co << 14) | (unsigned)p_row;
                        }
                    }
                }
            }
        }
}

// ---------- exact fp32 refine of prefiltered logits ----------------------------------
__global__ void refine_k(const unsigned* __restrict__ pcand, const int* __restrict__ pccnt,
                         Cand* cand, int* ccnt,
                         const ushort_t* __restrict__ fh, const ushort_t* __restrict__ fl,
                         const float* __restrict__ cls_w, const float* __restrict__ cls_b)
{
    int n = blockIdx.y;
    int id = blockIdx.x;
    if (id >= min(pccnt[n], CAP)) return;
    unsigned pc = pcand[n*CAP + id];
    int l  = pc >> 24;
    int co = (pc >> 14) & 0x3FF;
    int pr = pc & 0x3FFF;
    int W = d_W[l], WP = d_WP[l];
    int y = pr / W, x = pr % W;
    int tid = threadIdx.x;
    float acc = 0.f;
    for (int k = tid; k < 2304; k += 64) {
        int ci = k / 9, tap = k % 9;
        size_t ad = ((size_t)(n*PAD_N + d_POFF[l] + (y + tap/3)*WP + (x + tap%3)))*256 + ci;
        float f = h2f(fh[ad]) + h2f(fl[ad]);
        acc += f * cls_w[(size_t)co*2304 + ci*9 + tap];
    }
    for (int off = 32; off; off >>= 1) acc += __shfl_down(acc, off);
    if (tid == 0) {
        float logit = acc + cls_b[co];
        float score = 1.0f/(1.0f + expf(-logit));
        if (score > 0.05f) {
            int idx = atomicAdd(&ccnt[n], 1);
            if (idx < CAP) {
                Cand c; c.score = score; c.level = l;
                c.ai = pr*9 + co/91;
                c.lb = co % 91;
                c.b0 = c.b1 = c.b2 = c.b3 = 0.f;
                cand[n*CAP + idx] = c;
            }
        }
    }
}

// ---------- GN stats: fixed-order reduce, both towers (640 items), 64px-tile widx ----
__global__ void gn_stats_k(const float* __restrict__ partials, float* __restrict__ stats)
{
    int t = blockIdx.x*32 + threadIdx.x;
    if (t >= 640) return;
    int g = t & 31, n = (t >> 5) & 1, l = (t >> 6) % 5, tw = t / 320;
    int cot = g >> 4, gi = g & 15;
    int t2 = tw*4 + cot*2 + n;
    double S = 0.0, Q = 0.0;
    for (int pt = d_PT2[l]; pt < d_PT2[l+1]; ++pt) {
        int widx = pt*8 + t2;
        S += (double)partials[((size_t)widx*16 + gi)*2];
        Q += (double)partials[((size_t)widx*16 + gi)*2 + 1];
    }
    double cnt = 8.0 * (double)d_HW[l];
    double mean = S / cnt;
    double var = Q / cnt - mean*mean;
    stats[t*2]     = (float)mean;
    stats[t*2 + 1] = (float)(1.0 / sqrt(var + 1e-5));
}

// ---------- GN normalize + ReLU, in place on padded fp16 hi/lo, both towers ----------
__global__ __launch_bounds__(256)
void gn_norm_k(ushort_t* hC, ushort_t* lC, ushort_t* hR, ushort_t* lR,
               const float* __restrict__ stats,
               const float* __restrict__ gC, const float* __restrict__ bC,
               const float* __restrict__ gR, const float* __restrict__ bR)
{
    int total = 4*P_TOT*32;
    for (int idx = blockIdx.x*256 + threadIdx.x; idx < total; idx += gridDim.x*256) {
        int cs = idx & 31;
        int pix = (idx >> 5) % P_TOT;
        int rest = (idx >> 5) / P_TOT;
        int n = rest & 1, tw = rest >> 1;
        int l = 0; while (l < 4 && pix >= d_LOFF[l+1]) ++l;
        const float* st = stats + (size_t)(tw*320 + l*64 + n*32 + cs)*2;
        float mean = st[0], rstd = st[1];
        const float* gamma = tw ? gR : gC;
        const float* beta  = tw ? bR : bC;
        ushort_t* H = tw ? hR : hC;
        ushort_t* L = tw ? lR : lC;
        int p = pix - d_LOFF[l];
        int W = d_W[l], WP = d_WP[l];
        int y = p / W, x = p % W;
        size_t a = ((size_t)(n*PAD_N + d_POFF[l] + (y+1)*WP + (x+1)))*256 + cs*8;
        s16x8 vh = *(s16x8*)(H + a);
        s16x8 vl = *(s16x8*)(L + a);
#pragma unroll
        for (int j = 0; j < 8; ++j) {
            float v = h2f((ushort_t)vh[j]) + h2f((ushort_t)vl[j]);
            v = (v - mean)*rstd*gamma[cs*8 + j] + beta[cs*8 + j];
            v = v > 0.f ? v : 0.f;
            ushort_t h = f2h(v);
            vh[j] = (short)h;
            vl[j] = (short)f2h(v - h2f(h));
        }
        *(s16x8*)(H + a) = vh;
        *(s16x8*)(L + a) = vl;
    }
}

// ---------- per-candidate reg head + decode ------------------------------------------
__global__ void cand_reg_k(Cand* cand, const int* __restrict__ ccnt,
                           const ushort_t* __restrict__ fh, const ushort_t* __restrict__ fl,
                           const float* __restrict__ rw, const float* __restrict__ rb,
                           const float* __restrict__ anchors)
{
    int n = blockIdx.y;
    int id = blockIdx.x;
    int cnt = min(ccnt[n], CAP);
    if (id >= cnt) return;
    Cand c = cand[n*CAP + id];
    int l = c.level; int W = d_W[l], WP = d_WP[l];
    int pix = c.ai / 9, a = c.ai % 9;
    int y = pix / W, x = pix % W;
    int tid = threadIdx.x;
    float r0 = 0, r1 = 0, r2 = 0, r3 = 0;
    for (int k = tid; k < 2304; k += 64) {
        int ci = k / 9, tap = k % 9;
        size_t ad = ((size_t)(n*PAD_N + d_POFF[l] + (y + tap/3)*WP + (x + tap%3)))*256 + ci;
        float f = h2f(fh[ad]) + h2f(fl[ad]);
        r0 += f * rw[(a*4 + 0)*2304 + k];
        r1 += f * rw[(a*4 + 1)*2304 + k];
        r2 += f * rw[(a*4 + 2)*2304 + k];
        r3 += f * rw[(a*4 + 3)*2304 + k];
    }
    for (int off = 32; off; off >>= 1) {
        r0 += __shfl_down(r0, off);
        r1 += __shfl_down(r1, off);
        r2 += __shfl_down(r2, off);
        r3 += __shfl_down(r3, off);
    }
    if (tid == 0) {
        r0 += rb[a*4+0]; r1 += rb[a*4+1]; r2 += rb[a*4+2]; r3 += rb[a*4+3];
        const float* an = anchors + ((size_t)(d_LOFF[l]*9 + c.ai))*4;
        float aw = an[2]-an[0], ah = an[3]-an[1];
        float cx = an[0]+0.5f*aw, cy = an[1]+0.5f*ah;
        const float CLIP = 4.135166556742356f;
        float dw = fminf(r2, CLIP), dh = fminf(r3, CLIP);
        float pcx = r0*aw + cx, pcy = r1*ah + cy;
        float pw = expf(dw)*aw, ph2 = expf(dh)*ah;
        float b0 = pcx - 0.5f*pw, b1 = pcy - 0.5f*ph2;
        float b2 = pcx + 0.5f*pw, b3 = pcy + 0.5f*ph2;
        cand[n*CAP+id].b0 = fminf(fmaxf(b0, 0.f), 1216.f);
        cand[n*CAP+id].b1 = fminf(fmaxf(b1, 0.f), 800.f);
        cand[n*CAP+id].b2 = fminf(fmaxf(b2, 0.f), 1216.f);
        cand[n*CAP+id].b3 = fminf(fmaxf(b3, 0.f), 800.f);
    }
}

// ---------- NMS (exact replica of ref scan semantics) --------------------------------
__global__ __launch_bounds__(256)
void nms_k(const Cand* __restrict__ cand, const int* __restrict__ ccnt, float* __restrict__ out)
{
    int n = blockIdx.x;
    int tid = threadIdx.x;
    int cnt = min(ccnt[n], CAP);
    const Cand* cd = cand + n*CAP;
    __shared__ unsigned char alive[CAP];
    __shared__ unsigned long long rK[256];
    __shared__ int rI[256];
    __shared__ float selB[4];
    float* outB = out + n*1200;
    float* outS = out + 2400 + n*300;
    float* outL = out + 3000 + n*300;
    for (int i = tid; i < 1200; i += 256) outB[i] = 0.f;
    for (int i = tid; i < 300; i += 256) { outS[i] = 0.f; outL[i] = -1.f; }
    for (int i = tid; i < CAP; i += 256) alive[i] = (i < cnt) ? 1 : 0;
    __syncthreads();
    for (int t = 0; t < 300; ++t) {
        unsigned long long bk = 0ull; int bi = -1;
        for (int i = tid; i < cnt; i += 256) if (alive[i]) {
            unsigned flat = (unsigned)(cd[i].ai*91 + cd[i].lb);
            unsigned long long k = ((unsigned long long)__float_as_uint(cd[i].score) << 32)
                                 | (unsigned long long)(0x07FFFFFFu - (((unsigned)cd[i].level << 24) | flat));
            if (k > bk) { bk = k; bi = i; }
        }
        rK[tid] = bk; rI[tid] = bi;
        __syncthreads();
        for (int off = 128; off; off >>= 1) {
            if (tid < off && rK[tid+off] > rK[tid]) { rK[tid] = rK[tid+off]; rI[tid] = rI[tid+off]; }
            __syncthreads();
        }
        if (rK[0] == 0ull) break;
        if (tid == 0) {
            int j = rI[0];
            Cand s = cd[j];
            alive[j] = 0;
            outB[t*4+0] = s.b0; outB[t*4+1] = s.b1; outB[t*4+2] = s.b2; outB[t*4+3] = s.b3;
            outS[t] = s.score; outL[t] = (float)s.lb;
            float o = (float)s.lb * 2017.0f;
            selB[0] = s.b0+o; selB[1] = s.b1+o; selB[2] = s.b2+o; selB[3] = s.b3+o;
        }
        __syncthreads();
        float s0 = selB[0], s1 = selB[1], s2 = selB[2], s3 = selB[3];
        float a1 = (s2-s0)*(s3-s1);
        for (int i = tid; i < cnt; i += 256) if (alive[i]) {
            float o = (float)cd[i].lb * 2017.0f;
            float c0 = cd[i].b0+o, c1 = cd[i].b1+o, c2 = cd[i].b2+o, c3 = cd[i].b3+o;
            float ltx = fmaxf(s0,c0), lty = fmaxf(s1,c1);
            float rbx = fminf(s2,c2), rby = fminf(s3,c3);
            float w = fmaxf(rbx-ltx, 0.f), h = fmaxf(rby-lty, 0.f);
            float inter = w*h;
            float a2 = (c2-c0)*(c3-c1);
            float iou = inter/(a1 + a2 - inter + 1e-9f);
            if (iou > 0.5f) alive[i] = 0;
        }
        __syncthreads();
    }
}

// ---------- host ---------------------------------------------------------------------
extern "C" void kernel_launch(void* const* d_in, const int* in_sizes, int n_in,
                              void* d_out, int out_size, void* d_ws, size_t ws_size,
                              hipStream_t stream)
{
    const float* p[5];
    for (int i = 0; i < 5; ++i) p[i] = (const float*)d_in[i];
    const float* cls_tw = (const float*)d_in[5];
    const float* cls_tb = (const float*)d_in[6];
    const float* cls_gs = (const float*)d_in[7];
    const float* cls_gb = (const float*)d_in[8];
    const float* cls_w  = (const float*)d_in[9];
    const float* cls_b  = (const float*)d_in[10];
    const float* reg_tw = (const float*)d_in[11];
    const float* reg_tb = (const float*)d_in[12];
    const float* reg_gs = (const float*)d_in[13];
    const float* reg_gb = (const float*)d_in[14];
    const float* reg_w  = (const float*)d_in[15];
    const float* reg_b  = (const float*)d_in[16];
    const float* anchors= (const float*)d_in[17];

    size_t PADB = (size_t)2*PAD_N*256;        // elements per padded buffer
    char* ws = (char*)d_ws;
    ushort_t* P0h  = (ushort_t*)ws;           // padIn pair (reused as cls ping-pong)
    ushort_t* P0l  = P0h  + PADB;
    ushort_t* CAh  = P0l  + PADB;             // cls A pair
    ushort_t* CAl  = CAh  + PADB;
    ushort_t* RAh  = CAl  + PADB;             // reg A pair
    ushort_t* RAl  = RAh  + PADB;
    ushort_t* RBh  = RAl  + PADB;             // reg B pair
    ushort_t* RBl  = RBh  + PADB;
    ushort_t* wtbH = RBl  + PADB;             // all weights (fp16 hi), 2944 rows
    float*    partials = (float*)(wtbH + (size_t)2944*2304);
    float*    stats    = partials + (size_t)2552*16*2;
    Cand*     cand     = (Cand*)(stats + 640*2);
    unsigned* pcand    = (unsigned*)(cand + 2*CAP);
    int*      ccnt     = (int*)(pcand + 2*CAP);     // [0,1]=refined, [2,3]=prefilter
    size_t need = (size_t)((char*)(ccnt + 4) - ws);
    if (ws_size < need) {                     // diagnosable bail: sentinel output
        sentinel_k<<<(out_size + 255)/256, 256, 0, stream>>>((float*)d_out, out_size);
        return;
    }
    int* pccnt = ccnt + 2;

    PadPtrs zp; zp.p[0]=P0h; zp.p[1]=P0l; zp.p[2]=CAh; zp.p[3]=CAl;
               zp.p[4]=RAh; zp.p[5]=RAl; zp.p[6]=RBh; zp.p[7]=RBl;
    zero_pad_k<<<250,256,0,stream>>>(zp);
    hipMemsetAsync(ccnt, 0, 4*sizeof(int), stream);
    prepw_k<<<4096,256,0,stream>>>(cls_tw, reg_tw, cls_w, wtbH);

    LvlSrc sIn;
    for (int l = 0; l < 5; ++l) sIn.p[l] = p[l];
    conv_in_k<<<2048,256,0,stream>>>(sIn, P0h, P0l);

    // merged towers, ping-pong: L0 P0->{CA,RA}; L1 {CA,RA}->{P0,RB}; L2 {P0,RB}->{CA,RA}; L3 {CA,RA}->{P0,RB}
    const ushort_t* sH[2]; const ushort_t* sL[2]; ushort_t* dH[2]; ushort_t* dL[2];
    for (int i = 0; i < 4; ++i) {
        if (i == 0)      { sH[0]=P0h; sL[0]=P0l; sH[1]=P0h; sL[1]=P0l; dH[0]=CAh; dL[0]=CAl; dH[1]=RAh; dL[1]=RAl; }
        else if (i == 1) { sH[0]=CAh; sL[0]=CAl; sH[1]=RAh; sL[1]=RAl; dH[0]=P0h; dL[0]=P0l; dH[1]=RBh; dL[1]=RBl; }
        else if (i == 2) { sH[0]=P0h; sL[0]=P0l; sH[1]=RBh; sL[1]=RBl; dH[0]=CAh; dL[0]=CAl; dH[1]=RAh; dL[1]=RAl; }
        else             { sH[0]=CAh; sL[0]=CAl; sH[1]=RAh; sL[1]=RAl; dH[0]=P0h; dL[0]=P0l; dH[1]=RBh; dL[1]=RBl; }
        ConvArgs a;
        a.Ah[0]=sH[0]; a.Al[0]=sL[0]; a.Ah[1]=sH[1]; a.Al[1]=sL[1];
        a.Oh[0]=dH[0]; a.Ol[0]=dL[0]; a.Oh[1]=dH[1]; a.Ol[1]=dL[1];
        a.bias[0]=cls_tb + i*256; a.bias[1]=reg_tb + i*256;
        a.brow0[0]=i*256; a.brow0[1]=1024 + i*256;
        conv_tower_k<<<2552,256,0,stream>>>(a, wtbH, partials);
        gn_stats_k<<<20,32,0,stream>>>(partials, stats);
        gn_norm_k<<<4096,256,0,stream>>>(dH[0], dL[0], dH[1], dL[1], stats,
                                         cls_gs + i*256, cls_gb + i*256,
                                         reg_gs + i*256, reg_gb + i*256);
    }

    // final cls conv (single-pass) + prefilter; then exact fp32 refine
    conv_detect_k<<<2240,256,0,stream>>>(P0h, wtbH, cls_b, pcand, pccnt);
    refine_k<<<dim3(CAP,2),64,0,stream>>>(pcand, pccnt, cand, ccnt, P0h, P0l, cls_w, cls_b);

    cand_reg_k<<<dim3(CAP,2),64,0,stream>>>(cand, ccnt, RBh, RBl, reg_w, reg_b, anchors);
    nms_k<<<2,256,0,stream>>>(cand, ccnt, (float*)d_out);
}

// Round 12
// 1245.891 us; speedup vs baseline: 1.1038x; 1.1038x over previous
//
#include <hip/hip_runtime.h>
#include <hip/hip_fp16.h>
#include <math.h>

#define CAP 4096
#define P_TOT 20267
#define PAD_N 21267

typedef unsigned short ushort_t;
typedef __attribute__((ext_vector_type(8))) _Float16 f16x8;
typedef __attribute__((ext_vector_type(8))) short s16x8;
typedef __attribute__((ext_vector_type(4))) float f32x4;

struct LvlSrc { const float* p[5]; };
struct Cand { float score; int level; int ai; int lb; float b0,b1,b2,b3; };
struct ConvArgs {
    const ushort_t* Ah[2]; const ushort_t* Al[2];   // conv MFMA inputs (fp16 hi + lo)
    ushort_t* Oh[2]; ushort_t* Ol[2];               // epilogue stores hi+lo
    const float* bias[2];
    int brow0[2];
};
struct PadPtrs { ushort_t* p[8]; };

__constant__ int d_H[5]    = {100,50,25,13,7};
__constant__ int d_W[5]    = {152,76,38,19,10};
__constant__ int d_WP[5]   = {154,78,40,21,12};
__constant__ int d_HP[5]   = {102,52,27,15,9};
__constant__ int d_HW[5]   = {15200,3800,950,247,70};
__constant__ int d_LOFF[6] = {0,15200,19000,19950,20197,20267};
__constant__ int d_POFF[6] = {0,15708,19764,20844,21159,21267};
__constant__ int d_PT[6]   = {0,119,149,157,159,160};      // 128-px tiles cumsum
__constant__ int d_RC[6]   = {0,508,764,894,962,1000};     // border-ring pixel cumsum

__device__ __forceinline__ ushort_t f2h(float x) { return __half_as_ushort(__float2half(x)); }
__device__ __forceinline__ float h2f(ushort_t u) { return __half2float(__ushort_as_half(u)); }

// ---------- zero the 1-px halo ring of all 8 padded buffers --------------------------
__global__ void zero_pad_k(PadPtrs bufs)
{
    int idx = blockIdx.x*256 + threadIdx.x;          // 1000 ring px * 2 n * 32 cs
    if (idx >= 64000) return;
    int cs = idx & 31;
    int rest = idx >> 5;
    int n = rest & 1;
    int r = rest >> 1;
    int l = 0; while (l < 4 && r >= d_RC[l+1]) ++l;
    r -= d_RC[l];
    int WP = d_WP[l], HP = d_HP[l];
    int y, x;
    if (r < WP)            { y = 0;      x = r; }
    else if (r < 2*WP)     { y = HP-1;   x = r - WP; }
    else { int s = r - 2*WP; y = 1 + (s >> 1); x = (s & 1) ? WP-1 : 0; }
    size_t a = ((size_t)(n*PAD_N + d_POFF[l] + y*WP + x))*256 + cs*8;
    s16x8 z = (s16x8){0,0,0,0,0,0,0,0};
#pragma unroll
    for (int i = 0; i < 8; ++i) *(s16x8*)(bufs.p[i] + a) = z;
}

// ---------- ws-too-small sentinel ----------------------------------------------------
__global__ void sentinel_k(float* out, int nsz)
{
    int i = blockIdx.x*256 + threadIdx.x;
    if (i < nsz) out[i] = 12345.0f;
}

// ---------- one-shot weight prep (fp16 hi) -------------------------------------------
// rows [0,1024)=cls tower, [1024,2048)=reg tower, [2048,2944)=final cls
__global__ void prepw_k(const float* __restrict__ cls_tw, const float* __restrict__ reg_tw,
                        const float* __restrict__ cls_w, ushort_t* __restrict__ bh)
{
    size_t total = (size_t)2944*2304;
    for (size_t idx = (size_t)blockIdx.x*256 + threadIdx.x; idx < total; idx += (size_t)gridDim.x*256) {
        int k = (int)(idx % 2304); int row = (int)(idx / 2304);
        int tap = k >> 8; int ci = k & 255;
        float v;
        if (row < 1024)        v = cls_tw[(size_t)row*2304 + ci*9 + tap];
        else if (row < 2048)   v = reg_tw[(size_t)(row-1024)*2304 + ci*9 + tap];
        else { int co = row - 2048; v = (co < 819) ? cls_w[(size_t)co*2304 + ci*9 + tap] : 0.f; }
        bh[idx] = f2h(v);
    }
}

// ---------- input NCHW fp32 -> padded NHWC fp16 hi/lo --------------------------------
__global__ __launch_bounds__(256)
void conv_in_k(LvlSrc src, ushort_t* __restrict__ ph, ushort_t* __restrict__ pl)
{
    int total = 2*32*P_TOT;
    for (int idx = blockIdx.x*256 + threadIdx.x; idx < total; idx += gridDim.x*256) {
        int pix = idx % P_TOT;
        int cs  = (idx / P_TOT) & 31;
        int n   = idx / (32*P_TOT);
        int l = 0; while (l < 4 && pix >= d_LOFF[l+1]) ++l;
        int p = pix - d_LOFF[l];
        int W = d_W[l], WP = d_WP[l], HW = d_HW[l];
        int y = p / W, x = p % W;
        const float* sp = src.p[l];
        size_t a = ((size_t)(n*PAD_N + d_POFF[l] + (y+1)*WP + (x+1)))*256 + cs*8;
        s16x8 vh, vl;
#pragma unroll
        for (int j = 0; j < 8; ++j) {
            float v = sp[((size_t)(n*256 + cs*8 + j))*HW + p];
            ushort_t h = f2h(v);
            vh[j] = (short)h;
            vl[j] = (short)f2h(v - h2f(h));
        }
        *(s16x8*)(ph + a) = vh;
        *(s16x8*)(pl + a) = vl;
    }
}

// ---------- MFMA implicit-GEMM conv3x3, pt-major XCD chunks --------------------------
// DETECT=false: fp16-split 2-pass (towers, GN-partial epilogue).
// DETECT=true : fp16 single-pass + prefilter push (logit > -3.2; 60-sigma margin,
//               exact fp32 refine afterwards).
template<bool DETECT>
__global__ __launch_bounds__(256)
void convmfma_k(ConvArgs args, const ushort_t* __restrict__ Bh,
                float* __restrict__ partials, int q,
                const float* __restrict__ fbias, Cand* cand, int* ccnt)
{
    __shared__ __align__(16) ushort_t smem[(DETECT ? 2 : 3)*8192];
    ushort_t* sAh = smem;
    ushort_t* sAl = smem + 8192;                     // unused when DETECT
    ushort_t* sBh = smem + (DETECT ? 8192 : 16384);

    int b = blockIdx.x;
    int widx = (b & 7)*q + (b >> 3);                  // bijective XCD chunking (m204, r==0)
    int pt, t2, n, cot, tw, brow;
    if (!DETECT) {
        pt = widx >> 3; t2 = widx & 7;                // pt-major: 8 sibling blocks share A window
        n = t2 & 1; cot = (t2 >> 1) & 1; tw = t2 >> 2; brow = args.brow0[tw] + cot*128;
    } else {
        pt = widx / 14; t2 = widx - pt*14;            // 14 siblings (7 cot x 2 n) share A window
        n = t2 & 1; cot = t2 >> 1; tw = 0; brow = 2048 + cot*128;
    }

    int l = 0; while (l < 4 && pt >= d_PT[l+1]) ++l;
    int p0 = (pt - d_PT[l])*128;
    int Pl = d_HW[l], W = d_W[l], WP = d_WP[l];
    const ushort_t* Ah = args.Ah[tw];
    const ushort_t* Al = args.Al[tw];

    int tid = threadIdx.x;
    int w = tid >> 6, ln = tid & 63;
    int wr = w >> 1, wc = w & 1;

    size_t abase[4]; size_t bbase[4]; int ldso[4];
#pragma unroll
    for (int it = 0; it < 4; ++it) {
        int ch = (it*4 + w)*8 + (ln >> 3);
        int swz = ((ln & 7) ^ (ch & 7)) << 3;
        int p = min(p0 + ch, Pl - 1);
        int y = p / W, x = p % W;
        abase[it] = ((size_t)(n*PAD_N + d_POFF[l] + y*WP + x))*256 + swz;
        bbase[it] = ((size_t)(brow + ch))*2304 + swz;
        ldso[it]  = (it*4 + w)*1024;
    }

    int kbase = (ln >> 4) * 8;
    int rowA[4], xrA[4], rowB[4], xrB[4];
#pragma unroll
    for (int m = 0; m < 4; ++m) {
        int r = wr*64 + m*16 + (ln & 15);
        rowA[m] = r*64; xrA[m] = (r & 7) << 3;
    }
#pragma unroll
    for (int nf = 0; nf < 4; ++nf) {
        int r = wc*64 + nf*16 + (ln & 15);
        rowB[nf] = r*64; xrB[nf] = (r & 7) << 3;
    }

    f32x4 acc[4][4];
#pragma unroll
    for (int m = 0; m < 4; ++m)
#pragma unroll
        for (int nf = 0; nf < 4; ++nf) acc[m][nf] = (f32x4){0.f,0.f,0.f,0.f};

    // ks -> (ky, sl, kx): ks = ky*12 + sl*3 + kx
    auto stage = [&](int ks) {
        int ky = ks / 12;
        int rem = ks - ky*12;
        int sl = rem / 3;
        int kx = rem - sl*3;
        size_t adelta = (size_t)(ky*WP + kx)*256 + sl*64;
        size_t bdelta = (size_t)((ky*3 + kx)*256 + sl*64);
#pragma unroll
        for (int it = 0; it < 4; ++it) {
            __builtin_amdgcn_global_load_lds((const unsigned int*)(Ah + abase[it] + adelta),
                                             (unsigned int*)((char*)sAh + ldso[it]), 16, 0, 0);
            if constexpr (!DETECT)
                __builtin_amdgcn_global_load_lds((const unsigned int*)(Al + abase[it] + adelta),
                                                 (unsigned int*)((char*)sAl + ldso[it]), 16, 0, 0);
            __builtin_amdgcn_global_load_lds((const unsigned int*)(Bh + bbase[it] + bdelta),
                                             (unsigned int*)((char*)sBh + ldso[it]), 16, 0, 0);
        }
    };

    stage(0);
    for (int ks = 0; ks < 36; ++ks) {
        __syncthreads();                 // stage(ks) landed (barrier drains vmcnt)
        f16x8 a_h[2][4], a_l[2][4], b_h[2][4];
#pragma unroll
        for (int ks2 = 0; ks2 < 2; ++ks2) {
            int kb = kbase + ks2*32;
#pragma unroll
            for (int m = 0; m < 4; ++m) {
                int idx = rowA[m] + (kb ^ xrA[m]);
                a_h[ks2][m] = *(const f16x8*)&sAh[idx];
                if constexpr (!DETECT) a_l[ks2][m] = *(const f16x8*)&sAl[idx];
            }
#pragma unroll
            for (int nf = 0; nf < 4; ++nf) {
                int idx = rowB[nf] + (kb ^ xrB[nf]);
                b_h[ks2][nf] = *(const f16x8*)&sBh[idx];
            }
        }
        __syncthreads();                 // all waves' frag reads complete -> LDS reusable
        if (ks + 1 < 36) stage(ks + 1);  // issue next stage; flies under the MFMAs below
        __builtin_amdgcn_sched_barrier(0);  // pin: loads issued before MFMA cluster
#pragma unroll
        for (int ks2 = 0; ks2 < 2; ++ks2)
#pragma unroll
            for (int m = 0; m < 4; ++m)
#pragma unroll
                for (int nf = 0; nf < 4; ++nf) {
                    acc[m][nf] = __builtin_amdgcn_mfma_f32_16x16x32_f16(a_h[ks2][m], b_h[ks2][nf], acc[m][nf], 0, 0, 0);
                    if constexpr (!DETECT)
                        acc[m][nf] = __builtin_amdgcn_mfma_f32_16x16x32_f16(a_l[ks2][m], b_h[ks2][nf], acc[m][nf], 0, 0, 0);
                }
    }

    if constexpr (!DETECT) {
        ushort_t* Oh = args.Oh[tw];
        ushort_t* Ol = args.Ol[tw];
        const float* bias = args.bias[tw];
        float S[4] = {0,0,0,0}, Q[4] = {0,0,0,0};
#pragma unroll
        for (int m = 0; m < 4; ++m) {
            size_t pa[4]; bool ok[4];
#pragma unroll
            for (int r = 0; r < 4; ++r) {
                int p_row = p0 + wr*64 + m*16 + (ln >> 4)*4 + r;
                ok[r] = p_row < Pl;
                int pr = ok[r] ? p_row : 0;
                int y = pr / W, x = pr - y*W;
                pa[r] = ((size_t)(n*PAD_N + d_POFF[l] + (y+1)*WP + (x+1)))*256;
            }
#pragma unroll
            for (int nf = 0; nf < 4; ++nf) {
                int co = cot*128 + wc*64 + nf*16 + (ln & 15);
                float bs = bias[co];
#pragma unroll
                for (int r = 0; r < 4; ++r) if (ok[r]) {
                    float v = acc[m][nf][r] + bs;
                    ushort_t h = f2h(v);
                    Oh[pa[r] + co] = h;
                    Ol[pa[r] + co] = f2h(v - h2f(h));
                    S[nf] += v; Q[nf] += v*v;
                }
            }
        }
        __syncthreads();
        float* redS = (float*)smem;        // 2048
        float* redQ = redS + 2048;         // 2048
        float* colS = redQ + 2048;         // 128
        float* colQ = colS + 128;          // 128
#pragma unroll
        for (int nf = 0; nf < 4; ++nf) {
            int slot = ((wc*4 + nf)*16 + (ln & 15))*8 + wr*4 + (ln >> 4);
            redS[slot] = S[nf]; redQ[slot] = Q[nf];
        }
        __syncthreads();
        if (tid < 128) {
            float s = 0.f, qq = 0.f;
#pragma unroll
            for (int j = 0; j < 8; ++j) { s += redS[tid*8 + j]; qq += redQ[tid*8 + j]; }
            colS[tid] = s; colQ[tid] = qq;
        }
        __syncthreads();
        if (tid < 16) {
            float s = 0.f, qq = 0.f;
#pragma unroll
            for (int j = 0; j < 8; ++j) { s += colS[tid*8 + j]; qq += colQ[tid*8 + j]; }
            partials[((size_t)widx*16 + tid)*2]     = s;
            partials[((size_t)widx*16 + tid)*2 + 1] = qq;
        }
    } else {
        // prefilter: single-pass logit approx; margin 0.25 vs threshold -2.944 (~60 sigma)
        unsigned* pcand = (unsigned*)cand;
        int pixbase = p0 + wr*64;
#pragma unroll
        for (int m = 0; m < 4; ++m)
#pragma unroll
            for (int nf = 0; nf < 4; ++nf) {
                int co = cot*128 + wc*64 + nf*16 + (ln & 15);
                if (co < 819) {
                    float bs = fbias[co];
#pragma unroll
                    for (int r = 0; r < 4; ++r) {
                        int p_row = pixbase + m*16 + (ln >> 4)*4 + r;
                        if (p_row < Pl) {
                            float logit = acc[m][nf][r] + bs;
                            if (logit > -3.2f) {
                                int idx = atomicAdd(&ccnt[n], 1);
                                if (idx < CAP)
                                    pcand[n*CAP + idx] = ((unsigned)l << 24) | ((unsigned)co << 14) | (unsigned)p_row;
                            }
                        }
                    }
                }
            }
    }
}

// ---------- exact fp32 refine of prefiltered logits ----------------------------------
__global__ void refine_k(const unsigned* __restrict__ pcand, const int* __restrict__ pccnt,
                         Cand* cand, int* ccnt,
                         const ushort_t* __restrict__ fh, const ushort_t* __restrict__ fl,
                         const float* __restrict__ cls_w, const float* __restrict__ cls_b)
{
    int n = blockIdx.y;
    int id = blockIdx.x;
    if (id >= min(pccnt[n], CAP)) return;
    unsigned pc = pcand[n*CAP + id];
    int l  = pc >> 24;
    int co = (pc >> 14) & 0x3FF;
    int pr = pc & 0x3FFF;
    int W = d_W[l], WP = d_WP[l];
    int y = pr / W, x = pr % W;
    int tid = threadIdx.x;
    float acc = 0.f;
    for (int k = tid; k < 2304; k += 64) {
        int ci = k / 9, tap = k % 9;
        size_t ad = ((size_t)(n*PAD_N + d_POFF[l] + (y + tap/3)*WP + (x + tap%3)))*256 + ci;
        float f = h2f(fh[ad]) + h2f(fl[ad]);
        acc += f * cls_w[(size_t)co*2304 + ci*9 + tap];
    }
    for (int off = 32; off; off >>= 1) acc += __shfl_down(acc, off);
    if (tid == 0) {
        float logit = acc + cls_b[co];
        float score = 1.0f/(1.0f + expf(-logit));
        if (score > 0.05f) {
            int idx = atomicAdd(&ccnt[n], 1);
            if (idx < CAP) {
                Cand c; c.score = score; c.level = l;
                c.ai = pr*9 + co/91;
                c.lb = co % 91;
                c.b0 = c.b1 = c.b2 = c.b3 = 0.f;
                cand[n*CAP + idx] = c;
            }
        }
    }
}

// ---------- GN stats: fixed-order reduce, both towers (640 items), pt-major widx -----
__global__ void gn_stats_k(const float* __restrict__ partials, float* __restrict__ stats)
{
    int t = blockIdx.x*32 + threadIdx.x;
    if (t >= 640) return;
    int g = t & 31, n = (t >> 5) & 1, l = (t >> 6) % 5, tw = t / 320;
    int cot = g >> 4, gi = g & 15;
    int t2 = tw*4 + cot*2 + n;
    double S = 0.0, Q = 0.0;
    for (int pt = d_PT[l]; pt < d_PT[l+1]; ++pt) {
        int widx = pt*8 + t2;
        S += (double)partials[((size_t)widx*16 + gi)*2];
        Q += (double)partials[((size_t)widx*16 + gi)*2 + 1];
    }
    double cnt = 8.0 * (double)d_HW[l];
    double mean = S / cnt;
    double var = Q / cnt - mean*mean;
    stats[t*2]     = (float)mean;
    stats[t*2 + 1] = (float)(1.0 / sqrt(var + 1e-5));
}

// ---------- GN normalize + ReLU, in place on padded fp16 hi/lo, both towers ----------
__global__ __launch_bounds__(256)
void gn_norm_k(ushort_t* hC, ushort_t* lC, ushort_t* hR, ushort_t* lR,
               const float* __restrict__ stats,
               const float* __restrict__ gC, const float* __restrict__ bC,
               const float* __restrict__ gR, const float* __restrict__ bR)
{
    int total = 4*P_TOT*32;
    for (int idx = blockIdx.x*256 + threadIdx.x; idx < total; idx += gridDim.x*256) {
        int cs = idx & 31;
        int pix = (idx >> 5) % P_TOT;
        int rest = (idx >> 5) / P_TOT;
        int n = rest & 1, tw = rest >> 1;
        int l = 0; while (l < 4 && pix >= d_LOFF[l+1]) ++l;
        const float* st = stats + (size_t)(tw*320 + l*64 + n*32 + cs)*2;
        float mean = st[0], rstd = st[1];
        const float* gamma = tw ? gR : gC;
        const float* beta  = tw ? bR : bC;
        ushort_t* H = tw ? hR : hC;
        ushort_t* L = tw ? lR : lC;
        int p = pix - d_LOFF[l];
        int W = d_W[l], WP = d_WP[l];
        int y = p / W, x = p % W;
        size_t a = ((size_t)(n*PAD_N + d_POFF[l] + (y+1)*WP + (x+1)))*256 + cs*8;
        s16x8 vh = *(s16x8*)(H + a);
        s16x8 vl = *(s16x8*)(L + a);
#pragma unroll
        for (int j = 0; j < 8; ++j) {
            float v = h2f((ushort_t)vh[j]) + h2f((ushort_t)vl[j]);
            v = (v - mean)*rstd*gamma[cs*8 + j] + beta[cs*8 + j];
            v = v > 0.f ? v : 0.f;
            ushort_t h = f2h(v);
            vh[j] = (short)h;
            vl[j] = (short)f2h(v - h2f(h));
        }
        *(s16x8*)(H + a) = vh;
        *(s16x8*)(L + a) = vl;
    }
}

// ---------- per-candidate reg head + decode ------------------------------------------
__global__ void cand_reg_k(Cand* cand, const int* __restrict__ ccnt,
                           const ushort_t* __restrict__ fh, const ushort_t* __restrict__ fl,
                           const float* __restrict__ rw, const float* __restrict__ rb,
                           const float* __restrict__ anchors)
{
    int n = blockIdx.y;
    int id = blockIdx.x;
    int cnt = min(ccnt[n], CAP);
    if (id >= cnt) return;
    Cand c = cand[n*CAP + id];
    int l = c.level; int W = d_W[l], WP = d_WP[l];
    int pix = c.ai / 9, a = c.ai % 9;
    int y = pix / W, x = pix % W;
    int tid = threadIdx.x;
    float r0 = 0, r1 = 0, r2 = 0, r3 = 0;
    for (int k = tid; k < 2304; k += 64) {
        int ci = k / 9, tap = k % 9;
        size_t ad = ((size_t)(n*PAD_N + d_POFF[l] + (y + tap/3)*WP + (x + tap%3)))*256 + ci;
        float f = h2f(fh[ad]) + h2f(fl[ad]);
        r0 += f * rw[(a*4 + 0)*2304 + k];
        r1 += f * rw[(a*4 + 1)*2304 + k];
        r2 += f * rw[(a*4 + 2)*2304 + k];
        r3 += f * rw[(a*4 + 3)*2304 + k];
    }
    for (int off = 32; off; off >>= 1) {
        r0 += __shfl_down(r0, off);
        r1 += __shfl_down(r1, off);
        r2 += __shfl_down(r2, off);
        r3 += __shfl_down(r3, off);
    }
    if (tid == 0) {
        r0 += rb[a*4+0]; r1 += rb[a*4+1]; r2 += rb[a*4+2]; r3 += rb[a*4+3];
        const float* an = anchors + ((size_t)(d_LOFF[l]*9 + c.ai))*4;
        float aw = an[2]-an[0], ah = an[3]-an[1];
        float cx = an[0]+0.5f*aw, cy = an[1]+0.5f*ah;
        const float CLIP = 4.135166556742356f;
        float dw = fminf(r2, CLIP), dh = fminf(r3, CLIP);
        float pcx = r0*aw + cx, pcy = r1*ah + cy;
        float pw = expf(dw)*aw, ph2 = expf(dh)*ah;
        float b0 = pcx - 0.5f*pw, b1 = pcy - 0.5f*ph2;
        float b2 = pcx + 0.5f*pw, b3 = pcy + 0.5f*ph2;
        cand[n*CAP+id].b0 = fminf(fmaxf(b0, 0.f), 1216.f);
        cand[n*CAP+id].b1 = fminf(fmaxf(b1, 0.f), 800.f);
        cand[n*CAP+id].b2 = fminf(fmaxf(b2, 0.f), 1216.f);
        cand[n*CAP+id].b3 = fminf(fmaxf(b3, 0.f), 800.f);
    }
}

// ---------- NMS (exact replica of ref scan semantics) --------------------------------
__global__ __launch_bounds__(256)
void nms_k(const Cand* __restrict__ cand, const int* __restrict__ ccnt, float* __restrict__ out)
{
    int n = blockIdx.x;
    int tid = threadIdx.x;
    int cnt = min(ccnt[n], CAP);
    const Cand* cd = cand + n*CAP;
    __shared__ unsigned char alive[CAP];
    __shared__ unsigned long long rK[256];
    __shared__ int rI[256];
    __shared__ float selB[4];
    float* outB = out + n*1200;
    float* outS = out + 2400 + n*300;
    float* outL = out + 3000 + n*300;
    for (int i = tid; i < 1200; i += 256) outB[i] = 0.f;
    for (int i = tid; i < 300; i += 256) { outS[i] = 0.f; outL[i] = -1.f; }
    for (int i = tid; i < CAP; i += 256) alive[i] = (i < cnt) ? 1 : 0;
    __syncthreads();
    for (int t = 0; t < 300; ++t) {
        unsigned long long bk = 0ull; int bi = -1;
        for (int i = tid; i < cnt; i += 256) if (alive[i]) {
            unsigned flat = (unsigned)(cd[i].ai*91 + cd[i].lb);
            unsigned long long k = ((unsigned long long)__float_as_uint(cd[i].score) << 32)
                                 | (unsigned long long)(0x07FFFFFFu - (((unsigned)cd[i].level << 24) | flat));
            if (k > bk) { bk = k; bi = i; }
        }
        rK[tid] = bk; rI[tid] = bi;
        __syncthreads();
        for (int off = 128; off; off >>= 1) {
            if (tid < off && rK[tid+off] > rK[tid]) { rK[tid] = rK[tid+off]; rI[tid] = rI[tid+off]; }
            __syncthreads();
        }
        if (rK[0] == 0ull) break;
        if (tid == 0) {
            int j = rI[0];
            Cand s = cd[j];
            alive[j] = 0;
            outB[t*4+0] = s.b0; outB[t*4+1] = s.b1; outB[t*4+2] = s.b2; outB[t*4+3] = s.b3;
            outS[t] = s.score; outL[t] = (float)s.lb;
            float o = (float)s.lb * 2017.0f;
            selB[0] = s.b0+o; selB[1] = s.b1+o; selB[2] = s.b2+o; selB[3] = s.b3+o;
        }
        __syncthreads();
        float s0 = selB[0], s1 = selB[1], s2 = selB[2], s3 = selB[3];
        float a1 = (s2-s0)*(s3-s1);
        for (int i = tid; i < cnt; i += 256) if (alive[i]) {
            float o = (float)cd[i].lb * 2017.0f;
            float c0 = cd[i].b0+o, c1 = cd[i].b1+o, c2 = cd[i].b2+o, c3 = cd[i].b3+o;
            float ltx = fmaxf(s0,c0), lty = fmaxf(s1,c1);
            float rbx = fminf(s2,c2), rby = fminf(s3,c3);
            float w = fmaxf(rbx-ltx, 0.f), h = fmaxf(rby-lty, 0.f);
            float inter = w*h;
            float a2 = (c2-c0)*(c3-c1);
            float iou = inter/(a1 + a2 - inter + 1e-9f);
            if (iou > 0.5f) alive[i] = 0;
        }
        __syncthreads();
    }
}

// ---------- host ---------------------------------------------------------------------
extern "C" void kernel_launch(void* const* d_in, const int* in_sizes, int n_in,
                              void* d_out, int out_size, void* d_ws, size_t ws_size,
                              hipStream_t stream)
{
    const float* p[5];
    for (int i = 0; i < 5; ++i) p[i] = (const float*)d_in[i];
    const float* cls_tw = (const float*)d_in[5];
    const float* cls_tb = (const float*)d_in[6];
    const float* cls_gs = (const float*)d_in[7];
    const float* cls_gb = (const float*)d_in[8];
    const float* cls_w  = (const float*)d_in[9];
    const float* cls_b  = (const float*)d_in[10];
    const float* reg_tw = (const float*)d_in[11];
    const float* reg_tb = (const float*)d_in[12];
    const float* reg_gs = (const float*)d_in[13];
    const float* reg_gb = (const float*)d_in[14];
    const float* reg_w  = (const float*)d_in[15];
    const float* reg_b  = (const float*)d_in[16];
    const float* anchors= (const float*)d_in[17];

    size_t PADB = (size_t)2*PAD_N*256;        // elements per padded buffer
    char* ws = (char*)d_ws;
    ushort_t* P0h  = (ushort_t*)ws;           // padIn pair (reused as cls ping-pong)
    ushort_t* P0l  = P0h  + PADB;
    ushort_t* CAh  = P0l  + PADB;             // cls A pair
    ushort_t* CAl  = CAh  + PADB;
    ushort_t* RAh  = CAl  + PADB;             // reg A pair
    ushort_t* RAl  = RAh  + PADB;
    ushort_t* RBh  = RAl  + PADB;             // reg B pair
    ushort_t* RBl  = RBh  + PADB;
    ushort_t* wtbH = RBl  + PADB;             // all weights (fp16 hi), 2944 rows
    float*    partials = (float*)(wtbH + (size_t)2944*2304);
    float*    stats    = partials + (size_t)1280*16*2;
    Cand*     cand     = (Cand*)(stats + 640*2);
    unsigned* pcand    = (unsigned*)(cand + 2*CAP);
    int*      ccnt     = (int*)(pcand + 2*CAP);     // [0,1]=refined, [2,3]=prefilter
    size_t need = (size_t)((char*)(ccnt + 4) - ws);
    if (ws_size < need) {                     // diagnosable bail: sentinel output
        sentinel_k<<<(out_size + 255)/256, 256, 0, stream>>>((float*)d_out, out_size);
        return;
    }
    int* pccnt = ccnt + 2;

    PadPtrs zp; zp.p[0]=P0h; zp.p[1]=P0l; zp.p[2]=CAh; zp.p[3]=CAl;
               zp.p[4]=RAh; zp.p[5]=RAl; zp.p[6]=RBh; zp.p[7]=RBl;
    zero_pad_k<<<250,256,0,stream>>>(zp);
    hipMemsetAsync(ccnt, 0, 4*sizeof(int), stream);
    prepw_k<<<4096,256,0,stream>>>(cls_tw, reg_tw, cls_w, wtbH);

    LvlSrc sIn;
    for (int l = 0; l < 5; ++l) sIn.p[l] = p[l];
    conv_in_k<<<2048,256,0,stream>>>(sIn, P0h, P0l);

    // merged towers, ping-pong: L0 P0->{CA,RA}; L1 {CA,RA}->{P0,RB}; L2 {P0,RB}->{CA,RA}; L3 {CA,RA}->{P0,RB}
    const ushort_t* sH[2]; const ushort_t* sL[2]; ushort_t* dH[2]; ushort_t* dL[2];
    for (int i = 0; i < 4; ++i) {
        if (i == 0)      { sH[0]=P0h; sL[0]=P0l; sH[1]=P0h; sL[1]=P0l; dH[0]=CAh; dL[0]=CAl; dH[1]=RAh; dL[1]=RAl; }
        else if (i == 1) { sH[0]=CAh; sL[0]=CAl; sH[1]=RAh; sL[1]=RAl; dH[0]=P0h; dL[0]=P0l; dH[1]=RBh; dL[1]=RBl; }
        else if (i == 2) { sH[0]=P0h; sL[0]=P0l; sH[1]=RBh; sL[1]=RBl; dH[0]=CAh; dL[0]=CAl; dH[1]=RAh; dL[1]=RAl; }
        else             { sH[0]=CAh; sL[0]=CAl; sH[1]=RAh; sL[1]=RAl; dH[0]=P0h; dL[0]=P0l; dH[1]=RBh; dL[1]=RBl; }
        ConvArgs a;
        a.Ah[0]=sH[0]; a.Al[0]=sL[0]; a.Ah[1]=sH[1]; a.Al[1]=sL[1];
        a.Oh[0]=dH[0]; a.Ol[0]=dL[0]; a.Oh[1]=dH[1]; a.Ol[1]=dL[1];
        a.bias[0]=cls_tb + i*256; a.bias[1]=reg_tb + i*256;
        a.brow0[0]=i*256; a.brow0[1]=1024 + i*256;
        convmfma_k<false><<<1280,256,0,stream>>>(a, wtbH, partials, 160, nullptr, nullptr, nullptr);
        gn_stats_k<<<20,32,0,stream>>>(partials, stats);
        gn_norm_k<<<4096,256,0,stream>>>(dH[0], dL[0], dH[1], dL[1], stats,
                                         cls_gs + i*256, cls_gb + i*256,
                                         reg_gs + i*256, reg_gb + i*256);
    }

    // final cls conv (single-pass) + prefilter; then exact fp32 refine
    {
        ConvArgs a;
        a.Ah[0]=P0h; a.Al[0]=P0l; a.Ah[1]=P0h; a.Al[1]=P0l;
        a.Oh[0]=nullptr; a.Ol[0]=nullptr; a.Oh[1]=nullptr; a.Ol[1]=nullptr;
        a.bias[0]=nullptr; a.bias[1]=nullptr;
        a.brow0[0]=2048; a.brow0[1]=2048;
        convmfma_k<true><<<2240,256,0,stream>>>(a, wtbH, nullptr, 280, cls_b, (Cand*)pcand, pccnt);
    }
    refine_k<<<dim3(CAP,2),64,0,stream>>>(pcand, pccnt, cand, ccnt, P0h, P0l, cls_w, cls_b);

    cand_reg_k<<<dim3(CAP,2),64,0,stream>>>(cand, ccnt, RBh, RBl, reg_w, reg_b, anchors);
    nms_k<<<2,256,0,stream>>>(cand, ccnt, (float*)d_out);
}